// Round 5
// baseline (266.964 us; speedup 1.0000x reference)
//
#include <hip/hip_runtime.h>

// Problem constants (CausalAttention: B=4, S=2048, D_IN=D_OUT=1024, single head)
#define Bb 4
#define Ss 2048
#define Dd 1024

typedef unsigned short u16;
typedef __bf16 bf16x8 __attribute__((ext_vector_type(8)));
typedef float  f32x4  __attribute__((ext_vector_type(4)));

__device__ inline u16 f2bf(float f) {
  union { float f; unsigned u; } x; x.f = f;
  unsigned u = x.u;
  return (u16)((u + 0x7fffu + ((u >> 16) & 1u)) >> 16);  // RNE
}
__device__ inline float bf2f(u16 h) {
  union { unsigned u; float f; } x; x.u = ((unsigned)h) << 16;
  return x.f;
}

// async global->LDS, 16B per lane. LDS dest is wave-uniform base + lane*16:
// lane order must match LDS contiguity.
__device__ static inline void gl_lds16(const u16* g, u16* l) {
  __builtin_amdgcn_global_load_lds((__attribute__((address_space(1))) const void*)g,
                                   (__attribute__((address_space(3))) void*)l,
                                   16, 0, 0);
}

// raw barrier with compiler memory fences (does NOT drain vmcnt -- counted
// vmcnt gates keep staging loads in flight across it).
__device__ static inline void qbar() {
  asm volatile("" ::: "memory");
  __builtin_amdgcn_s_barrier();
  asm volatile("" ::: "memory");
}

template <int GATEN>
__device__ __forceinline__ void qk_gate() {
  if constexpr (GATEN == 7) asm volatile("s_waitcnt vmcnt(7)" ::: "memory");
  else if constexpr (GATEN == 5) asm volatile("s_waitcnt vmcnt(5)" ::: "memory");
  else if constexpr (GATEN == 0) asm volatile("s_waitcnt vmcnt(0)" ::: "memory");
}

// ---------------- cast fp32 -> bf16 (x + 3 weights) + lsum zeroing ----------------
// wb is written as the STACKED [3072][1024] matrix wq|wk|wv -- qkv_fused uses it
// as a single fused B operand.
__global__ __launch_bounds__(256) void cast_all(const float* __restrict__ x,
                                                const float* __restrict__ wq,
                                                const float* __restrict__ wk,
                                                const float* __restrict__ wv,
                                                u16* __restrict__ xb,
                                                u16* __restrict__ wb,
                                                float* __restrict__ lsum) {
  int id = blockIdx.x;
  if (id < 8) {
    float4 z = {0.f, 0.f, 0.f, 0.f};
    ((float4*)lsum)[id * 256 + threadIdx.x] = z;
  }
  const float* src; u16* dst; int off;
  if (id < 2048) {                      // x: 8M elements
    src = x; dst = xb; off = id * 4096;
  } else {                              // weights: 1M each, 256 blocks per W
    int wi = id - 2048;
    int w = wi >> 8;
    src = (w == 0) ? wq : (w == 1) ? wk : wv;
    dst = wb + (size_t)w * Dd * Dd;
    off = (wi & 255) * 4096;
  }
#pragma unroll
  for (int t = 0; t < 4; t++) {
    int i = off + t * 1024 + threadIdx.x * 4;
    float4 v = *(const float4*)(src + i);
    unsigned p0 = (unsigned)f2bf(v.x) | ((unsigned)f2bf(v.y) << 16);
    unsigned p1 = (unsigned)f2bf(v.z) | ((unsigned)f2bf(v.w) << 16);
    uint2 p; p.x = p0; p.y = p1;
    *(uint2*)(dst + i) = p;
  }
}

// ---------------- shared GEMM core (C = A * B^T), bf16 in, fp32 acc ----------------
// (m97-style 128x128 core -- used by scores_fused and pv_gemm.)
#define BM 128
#define BN 128

__device__ inline void gemm_tile(const u16* __restrict__ A, int lda,
                                 const u16* __restrict__ Bp, int ldb,
                                 int kBeg, int kEnd,  // multiples of 64
                                 u16* lds, f32x4 acc[4][4]) {
  u16* lA0 = lds;
  u16* lB0 = lds + 4096;
  u16* lA1 = lds + 8192;
  u16* lB1 = lds + 12288;
  const int tid  = threadIdx.x;
  const int lane = tid & 63, wave = tid >> 6;
  const int quad = lane >> 4, r16 = lane & 15;
  const int wm = (wave & 1) * 64, wn = (wave >> 1) * 64;
  const int r0 = tid >> 2, part = tid & 3;  // seg s=q*256+tid -> row=q*64+r0

  for (int k0 = kBeg; k0 < kEnd; k0 += 64) {
    __syncthreads();  // previous halves' ds_reads done before overwrite
#pragma unroll
    for (int q = 0; q < 2; q++) {
      int row = q * 64 + r0;
      int s8 = (q * 256 + tid) * 8;
      const u16* ga = A  + (size_t)row * lda + k0 + part * 8;
      const u16* gb = Bp + (size_t)row * ldb + k0 + part * 8;
      gl_lds16(ga,      lA0 + s8);
      gl_lds16(gb,      lB0 + s8);
      gl_lds16(ga + 32, lA1 + s8);
      gl_lds16(gb + 32, lB1 + s8);
    }
    __syncthreads();
#pragma unroll
    for (int h = 0; h < 2; h++) {
      const u16* la = h ? lA1 : lA0;
      const u16* lb = h ? lB1 : lB0;
      bf16x8 fa[4], fb[4];
#pragma unroll
      for (int t = 0; t < 4; t++)
        fa[t] = *(const bf16x8*)(la + (wm + t * 16 + r16) * 32 + quad * 8);
#pragma unroll
      for (int t = 0; t < 4; t++)
        fb[t] = *(const bf16x8*)(lb + (wn + t * 16 + r16) * 32 + quad * 8);
#pragma unroll
      for (int tm = 0; tm < 4; tm++)
#pragma unroll
        for (int tn = 0; tn < 4; tn++)
          acc[tm][tn] = __builtin_amdgcn_mfma_f32_16x16x32_bf16(fa[tm], fb[tn],
                                                                acc[tm][tn], 0, 0, 0);
    }
  }
}

// ---------------- QKV projection: ONE fused GEMM, 256x384 tile ------------------
// r4 post-mortem: (1) acc[8][6]=192 regs vs VGPR_Count=128 => accumulator SPILL
// (evidence: +28MB FETCH, +19MB WRITE vs r2). Fixed via amdgpu_waves_per_eu(2)
// (256-reg budget at 2 waves/EU; launch_bounds 2nd arg gave 128 both ways).
// (2) serial-lockstep model fits r2 AND r4: {reads; BAR; MFMA; BAR} serializes
// T_lds (~1790cy) + T_mfma (~1863cy) per K32 => util capped ~50%.
// Fix: intra-wave pipelining. Each K32 region = 4 clusters of 12 MFMA
// (faA/faB x fbL/fbH); reads for cluster s+1 issue BEFORE cluster s's MFMAs
// (compiler inserts counted lgkm waits). Cross-region faA(T+1) prefetch sits
// after {vmcnt gate; BARRIER} -- the gate is per-wave, so only after every
// wave passes its own gate are all gl_lds writes for tile T+1 known-landed.
// Region layout (2 barriers):
//   s0: read fbL,fbH(T);            12 MFMA (faA x fbL)
//   s1: read faB(T); stgB(T+2);     12 MFMA (faA x fbH)
//   s2: stgA(T+3); gate; BAR; prefetch faA(T+1); 12 MFMA (faB x fbL)
//   s3:                             12 MFMA (faB x fbH); BAR
// Gate ledger: prologue stages A0,B0,A1,B1,A2 (12 ops), gate7 => tile0 landed.
// Region T gate7 leaves {A(T+2):2,B(T+2):3,A(T+3):2} => tile T+1 landed.
// Tails: T=29 gate5 => tile30; T=30 gate0 => tile31; T=31 no gate/prefetch.
// WAR (drift bounded by 2 bars/region): stgA(T+3)->buf(T-1)&3, whose reads
// (faA prefetched at T-2 s2, consumed T-1 s0/s1; faB read+consumed T-1 s1..s3)
// complete before region T-1's end BAR < region T s2 issue. stgB(T+2)->
// buf(T-1)%3: fb(T-1) read s0, consumed by s3 MFMA before end BAR. Safe.
// Swizzle (0 conflicts measured): 16B chunk c stored at c ^ ((row>>1)&3),
// applied on global source (gl_lds dest linear) and on ds_read (involution).
#define QBK 32
#define ABUF 8192   // u16 per A ring slot (256 x 32)
#define BBUF 12288  // u16 per B ring slot (384 x 32)

__global__ __launch_bounds__(512)
__attribute__((amdgpu_waves_per_eu(2)))
void qkv_fused(const u16* __restrict__ xb,
               const u16* __restrict__ wb,
               u16* __restrict__ qkv) {
  __shared__ __align__(16) u16 sh[4 * ABUF + 3 * BBUF];  // 139264 B = 136 KiB

  const int id  = blockIdx.x;                  // 0..255
  const int nt  = id & 7, mt = id >> 3;        // nt pinned per-XCD: B-panel
  const int row0 = mt * 256, col0 = nt * 384;  //   (0.75 MB) stays L2-resident
  const u16* A  = xb + (size_t)row0 * Dd;
  const u16* Bp = wb + (size_t)col0 * Dd;

  const int tid  = threadIdx.x;
  const int lane = tid & 63, wave = tid >> 6;
  const int wr = wave >> 2, wc = wave & 3;     // 2M x 4N wave grid
  const int quad = lane >> 4, r16 = lane & 15;

  // staging sources: slot p -> row=p>>2, phys chunk=p&3; source holds logical
  // chunk (p&3) ^ ((row>>1)&3). A slots {tid, tid+512}; B slots {tid, tid+512,
  // tid+1024}.
  const int rA0 = tid >> 2,          cA0 = tid & 3;
  const int rA1 = (tid + 512) >> 2,  cA1 = tid & 3;
  const int rB2 = (tid + 1024) >> 2;
  const u16* aS0 = A  + (size_t)rA0 * Dd + (size_t)((cA0 ^ ((rA0 >> 1) & 3)) * 8);
  const u16* aS1 = A  + (size_t)rA1 * Dd + (size_t)((cA1 ^ ((rA1 >> 1) & 3)) * 8);
  const u16* bS0 = Bp + (size_t)rA0 * Dd + (size_t)((cA0 ^ ((rA0 >> 1) & 3)) * 8);
  const u16* bS1 = Bp + (size_t)rA1 * Dd + (size_t)((cA1 ^ ((rA1 >> 1) & 3)) * 8);
  const u16* bS2 = Bp + (size_t)rB2 * Dd + (size_t)((cA0 ^ ((rB2 >> 1) & 3)) * 8);

  auto stgA = [&](int S) {
    u16* d = sh + (S & 3) * ABUF;
    const size_t ko = (size_t)S * QBK;
    gl_lds16(aS0 + ko, d + tid * 8);
    gl_lds16(aS1 + ko, d + (tid + 512) * 8);
  };
  auto stgB = [&](int S) {
    u16* d = sh + 4 * ABUF + ((unsigned)S % 3u) * BBUF;
    const size_t ko = (size_t)S * QBK;
    gl_lds16(bS0 + ko, d + tid * 8);
    gl_lds16(bS1 + ko, d + (tid + 512) * 8);
    gl_lds16(bS2 + ko, d + (tid + 1024) * 8);
  };

  // ds_read fragment bases (rows of 32 u16; swizzled 16B chunk). Row bases are
  // multiples of 16 -> (row>>1)&3 == (r16>>1)&3.
  const int chq  = (quad ^ ((r16 >> 1) & 3)) * 8;
  const int idxA = (wr * 128 + r16) * 32 + chq;   // + m*512, within A slot
  const int idxB = (wc * 96  + r16) * 32 + chq;   // + n*512, within B slot

  f32x4 acc[8][6];
#pragma unroll
  for (int m = 0; m < 8; m++)
#pragma unroll
    for (int n = 0; n < 6; n++) acc[m][n] = (f32x4){0.f, 0.f, 0.f, 0.f};
  bf16x8 faA[4], faB[4], fbL[3], fbH[3];

#define REGION(T_, DO_B, DO_A, GATEN, DO_PF)                                   \
  {                                                                            \
    const u16* lA = sh + ((T_) & 3) * ABUF;                                    \
    const u16* lB = sh + 4 * ABUF + ((unsigned)(T_) % 3u) * BBUF;              \
    /* s0 */                                                                   \
    _Pragma("unroll") for (int n = 0; n < 3; n++)                              \
        fbL[n] = *(const bf16x8*)(lB + idxB + n * 512);                        \
    _Pragma("unroll") for (int n = 0; n < 3; n++)                              \
        fbH[n] = *(const bf16x8*)(lB + idxB + (n + 3) * 512);                  \
    __builtin_amdgcn_s_setprio(1);                                             \
    _Pragma("unroll") for (int m = 0; m < 4; m++)                              \
      _Pragma("unroll") for (int n = 0; n < 3; n++)                            \
        acc[m][n] = __builtin_amdgcn_mfma_f32_16x16x32_bf16(faA[m], fbL[n],    \
                                                            acc[m][n], 0, 0, 0); \
    __builtin_amdgcn_s_setprio(0);                                             \
    /* s1 */                                                                   \
    _Pragma("unroll") for (int m = 0; m < 4; m++)                              \
        faB[m] = *(const bf16x8*)(lA + idxA + (m + 4) * 512);                  \
    if (DO_B) stgB((T_) + 2);                                                  \
    __builtin_amdgcn_s_setprio(1);                                             \
    _Pragma("unroll") for (int m = 0; m < 4; m++)                              \
      _Pragma("unroll") for (int n = 0; n < 3; n++)                            \
        acc[m][n + 3] = __builtin_amdgcn_mfma_f32_16x16x32_bf16(faA[m], fbH[n], \
                                                            acc[m][n + 3], 0, 0, 0); \
    __builtin_amdgcn_s_setprio(0);                                             \
    /* s2 */                                                                   \
    if (DO_A) stgA((T_) + 3);                                                  \
    qk_gate<GATEN>();                                                          \
    qbar();                                                                    \
    if (DO_PF) {                                                               \
      const u16* lA1_ = sh + (((T_) + 1) & 3) * ABUF;                          \
      _Pragma("unroll") for (int m = 0; m < 4; m++)                            \
          faA[m] = *(const bf16x8*)(lA1_ + idxA + m * 512);                    \
    }                                                                          \
    __builtin_amdgcn_s_setprio(1);                                             \
    _Pragma("unroll") for (int m = 0; m < 4; m++)                              \
      _Pragma("unroll") for (int n = 0; n < 3; n++)                            \
        acc[m + 4][n] = __builtin_amdgcn_mfma_f32_16x16x32_bf16(faB[m], fbL[n], \
                                                            acc[m + 4][n], 0, 0, 0); \
    __builtin_amdgcn_s_setprio(0);                                             \
    /* s3 */                                                                   \
    __builtin_amdgcn_s_setprio(1);                                             \
    _Pragma("unroll") for (int m = 0; m < 4; m++)                              \
      _Pragma("unroll") for (int n = 0; n < 3; n++)                            \
        acc[m + 4][n + 3] = __builtin_amdgcn_mfma_f32_16x16x32_bf16(faB[m], fbH[n], \
                                                            acc[m + 4][n + 3], 0, 0, 0); \
    __builtin_amdgcn_s_setprio(0);                                             \
    qbar();                                                                    \
  }

  // prologue: stage A0,B0,A1,B1,A2 (12 loads); own-gate(7) => this wave's
  // tile0 ops landed; BAR => ALL waves' tile0 landed; preload faA(0).
  stgA(0); stgB(0); stgA(1); stgB(1); stgA(2);
  qk_gate<7>();
  qbar();
#pragma unroll
  for (int m = 0; m < 4; m++)
    faA[m] = *(const bf16x8*)(sh + idxA + m * 512);

#pragma unroll 1
  for (int T = 0; T < 29; T++) REGION(T, true, true, 7, true);
  REGION(29, true,  false, 5, true)
  REGION(30, false, false, 0, true)
  REGION(31, false, false, -1, false)
#undef REGION

  // epilogue: fused column cc in [0,3072) -> weight zi = cc>>10, col cc&1023
#pragma unroll
  for (int m = 0; m < 8; m++) {
    int rr = row0 + wr * 128 + m * 16 + quad * 4;
#pragma unroll
    for (int n = 0; n < 6; n++) {
      int cc = col0 + wc * 96 + n * 16 + r16;
      u16* o = qkv + (size_t)(cc >> 10) * ((size_t)Bb * Ss * Dd) + (cc & 1023);
#pragma unroll
      for (int r = 0; r < 4; r++)
        o[(size_t)(rr + r) * Dd] = f2bf(acc[m][n][r]);
    }
  }
}

// ---------------- fused scores + rowsum + V-transpose ----------------
// Blocks [0,544): lower-tri score tiles -> sc = exp(QK^T/32) (diag masked),
//   per-row partial sums atomically added into lsum (bf16-rounded p summed so
//   numerator/denominator rounding match).
// Blocks [544,1024): V transpose, grid-stride over 2048 64x64 tiles.
__global__ __launch_bounds__(256) void scores_fused(const u16* __restrict__ qb,
                                                    const u16* __restrict__ kb,
                                                    const u16* __restrict__ vb,
                                                    u16* __restrict__ sc,
                                                    u16* __restrict__ vt,
                                                    float* __restrict__ lsum) {
  __shared__ __align__(16) u16 shmem[16384];
  const int id = blockIdx.x;
  const int tid = threadIdx.x;

  if (id >= 544) {  // ---- transpose role ----
    const int bid = id - 544;            // 0..479
    u16 (*t)[72] = (u16(*)[72])shmem;    // 64x72 u16 = 9216 <= 16384
    for (int u = bid; u < 2048; u += 480) {
      const int b = u >> 9, rem = u & 511;
      const int e0 = (rem >> 5) * 64, s0 = (rem & 31) * 64;
      const u16* src = vb + (size_t)b * Ss * Dd;
      u16* dst = vt + (size_t)b * Dd * Ss;
      if (u != bid) __syncthreads();
#pragma unroll
      for (int gg = tid; gg < 512; gg += 256) {
        int row = gg >> 3, prt = gg & 7;
        uint4 v = *(const uint4*)(src + (size_t)(s0 + row) * Dd + e0 + prt * 8);
        const u16* pv = (const u16*)&v;
#pragma unroll
        for (int jj = 0; jj < 8; jj++) t[prt * 8 + jj][row] = pv[jj];
      }
      __syncthreads();
#pragma unroll
      for (int gg = tid; gg < 512; gg += 256) {
        int ee = gg >> 3, prt = gg & 7;
        uint4 v = *(const uint4*)(&t[ee][prt * 8]);
        *(uint4*)(dst + (size_t)(e0 + ee) * Ss + s0 + prt * 8) = v;
      }
    }
    return;
  }

  // ---- scores role ----
  // XCD swizzle: 17 consecutive tri-ids per XCD per batch (136 = 8*17).
  const int xcd = id & 7, j = id >> 3;   // j 0..67
  const int b = j / 17, tloc = j - b * 17;
  const int t = xcd * 17 + tloc;         // 0..135 lower-tri index
  int it = (int)((sqrtf(8.f * (float)t + 1.f) - 1.f) * 0.5f);
  while ((it + 1) * (it + 2) / 2 <= t) it++;
  while (it * (it + 1) / 2 > t) it--;
  const int jt = t - it * (it + 1) / 2;

  const u16* A  = qb + (size_t)b * Ss * Dd + (size_t)it * BM * Dd;
  const u16* Bp = kb + (size_t)b * Ss * Dd + (size_t)jt * BN * Dd;
  f32x4 acc[4][4];
  const f32x4 zero = {0.f, 0.f, 0.f, 0.f};
#pragma unroll
  for (int tm = 0; tm < 4; tm++)
#pragma unroll
    for (int tn = 0; tn < 4; tn++) acc[tm][tn] = zero;

  gemm_tile(A, Dd, Bp, Dd, 0, Dd, shmem, acc);

  // Unnormalized exp (|s/32| << 88 so fp32 exp safe without max-subtraction).
  u16* out = sc + (size_t)b * Ss * Ss;
  float* lr = lsum + (size_t)b * Ss;
  const int lane = tid & 63, wave = tid >> 6;
  const int quad = lane >> 4, r16 = lane & 15;
  const int wm = (wave & 1) * 64, wn = (wave >> 1) * 64;
#pragma unroll
  for (int tm = 0; tm < 4; tm++) {
    float psum[4] = {0.f, 0.f, 0.f, 0.f};  // per r, summed over tn
#pragma unroll
    for (int tn = 0; tn < 4; tn++) {
      int rr = it * BM + wm + tm * 16 + quad * 4;
      int cc = jt * BN + wn + tn * 16 + r16;
#pragma unroll
      for (int r = 0; r < 4; r++) {
        float p = 0.f;
        u16 h = 0;
        if (cc <= rr + r) {
          h = f2bf(__expf(acc[tm][tn][r] * 0.03125f));
          p = bf2f(h);  // sum the bf16-rounded value (matches stored numerator)
        }
        out[(size_t)(rr + r) * Ss + cc] = h;
        psum[r] += p;
      }
    }
#pragma unroll
    for (int r = 0; r < 4; r++) {
      float s = psum[r];
      s += __shfl_xor(s, 1);
      s += __shfl_xor(s, 2);
      s += __shfl_xor(s, 4);
      s += __shfl_xor(s, 8);
      if (r16 == 0) {
        int row = it * BM + wm + tm * 16 + quad * 4 + r;
        atomicAdd(&lr[row], s);
      }
    }
  }
}

// ---------------- PV: O[q,e] = (1/l[q]) * sum_k sc[q,k] Vt[e,k] ----------------
// XCD-grouped schedule: xcd=idx&7, slot=idx>>3; qp=slot>>3 (0..7), col=slot&7.
// b=qp&3, it=(qp>>2)?15-xcd:xcd. The 8 col-tiles of one (b,it) are consecutive
// slots on ONE XCD -> sc A-panel fetched ~once from HBM (not 8x) and vt[b]
// reused in that XCD's L2. Each XCD gets its {xcd, 15-xcd} -> uniform 17
// tile-K per XCD regardless of block->CU pairing granularity.
__global__ __launch_bounds__(256) void pv_gemm(const u16* __restrict__ sc,
                                               const u16* __restrict__ vt,
                                               const float* __restrict__ lsum,
                                               float* __restrict__ out) {
  __shared__ __align__(16) u16 shmem[16384];
  const int idx = blockIdx.x;            // 0..511
  const int xcd = idx & 7, slot = idx >> 3;
  const int qp = slot >> 3, col = slot & 7;
  const int b = qp & 3;
  const int it = (qp >> 2) ? (15 - xcd) : xcd;
  const int row0 = it * BM;
  const int col0 = col * BN;             // N = 1024
  const u16* A  = sc + (size_t)b * Ss * Ss + (size_t)row0 * Ss;
  const u16* Bp = vt + (size_t)b * Dd * Ss + (size_t)col0 * Ss;
  f32x4 acc[4][4];
  const f32x4 zero = {0.f, 0.f, 0.f, 0.f};
#pragma unroll
  for (int tm = 0; tm < 4; tm++)
#pragma unroll
    for (int tn = 0; tn < 4; tn++) acc[tm][tn] = zero;

  // causal: P[q,k]==0 for k > q (incl. zero-filled diag tile), K-loop clipped
  gemm_tile(A, Ss, Bp, Ss, 0, row0 + BM, shmem, acc);

  float* o = out + (size_t)b * Ss * Dd;
  const float* lr = lsum + (size_t)b * Ss;
  const int lane = threadIdx.x & 63, wave = threadIdx.x >> 6;
  const int quad = lane >> 4, r16 = lane & 15;
  const int wm = (wave & 1) * 64, wn = (wave >> 1) * 64;
#pragma unroll
  for (int tm = 0; tm < 4; tm++) {
    int rbase = row0 + wm + tm * 16 + quad * 4;
    float s0 = 1.f / lr[rbase], s1 = 1.f / lr[rbase + 1];
    float s2 = 1.f / lr[rbase + 2], s3 = 1.f / lr[rbase + 3];
#pragma unroll
    for (int tn = 0; tn < 4; tn++) {
      int cc = col0 + wn + tn * 16 + r16;
      o[(size_t)(rbase + 0) * Dd + cc] = acc[tm][tn][0] * s0;
      o[(size_t)(rbase + 1) * Dd + cc] = acc[tm][tn][1] * s1;
      o[(size_t)(rbase + 2) * Dd + cc] = acc[tm][tn][2] * s2;
      o[(size_t)(rbase + 3) * Dd + cc] = acc[tm][tn][3] * s3;
    }
  }
}

// ---------------- launch ----------------
// Workspace layout (bytes), total 106,987,520 (~102 MB):
//   qkv : [0, 50331648)           q,k,v bf16, each 16 MB
//   sc  : [50331648, 83886080)    exp-scores bf16, 32 MB
//   xb  : [83886080, 100663296)   x bf16 16 MB; REUSED as vt after qkv_fused
//   wb  : [100663296, 106954752)  wq|wk|wv bf16 stacked [3072][1024], 6 MB
//   lsum: [106954752, 106987520)  per-row sum fp32, 32 KB (zeroed by cast_all)
extern "C" void kernel_launch(void* const* d_in, const int* in_sizes, int n_in,
                              void* d_out, int out_size, void* d_ws, size_t ws_size,
                              hipStream_t stream) {
  const float* x  = (const float*)d_in[0];
  const float* wq = (const float*)d_in[1];
  const float* wk = (const float*)d_in[2];
  const float* wv = (const float*)d_in[3];
  float* out = (float*)d_out;
  char* ws = (char*)d_ws;
  if (ws_size < 106987520u) return;  // clean fail rather than OOB corruption

  u16* qkv  = (u16*)(ws);
  u16* sc   = (u16*)(ws + 50331648u);
  u16* xb   = (u16*)(ws + 83886080u);
  u16* vt   = xb;  // alias: x dead after qkv_fused
  u16* wb   = (u16*)(ws + 100663296u);
  float* lsum = (float*)(ws + 106954752u);

  const size_t nQ = (size_t)Bb * Ss * Dd;  // 8388608

  cast_all<<<2816, 256, 0, stream>>>(x, wq, wk, wv, xb, wb, lsum);
  qkv_fused<<<256, 512, 0, stream>>>(xb, wb, qkv);
  scores_fused<<<1024, 256, 0, stream>>>(qkv, qkv + nQ, qkv + 2 * nQ, sc, vt, lsum);
  pv_gemm<<<512, 256, 0, stream>>>(sc, vt, lsum, out);
}

// Round 6
// 233.846 us; speedup vs baseline: 1.1416x; 1.1416x over previous
//
#include <hip/hip_runtime.h>

// Problem constants (CausalAttention: B=4, S=2048, D_IN=D_OUT=1024, single head)
#define Bb 4
#define Ss 2048
#define Dd 1024

typedef unsigned short u16;
typedef __bf16 bf16x8 __attribute__((ext_vector_type(8)));
typedef float  f32x4  __attribute__((ext_vector_type(4)));

__device__ inline u16 f2bf(float f) {
  union { float f; unsigned u; } x; x.f = f;
  unsigned u = x.u;
  return (u16)((u + 0x7fffu + ((u >> 16) & 1u)) >> 16);  // RNE
}
__device__ inline float bf2f(u16 h) {
  union { unsigned u; float f; } x; x.u = ((unsigned)h) << 16;
  return x.f;
}

// async global->LDS, 16B per lane. LDS dest is wave-uniform base + lane*16:
// lane order must match LDS contiguity.
__device__ static inline void gl_lds16(const u16* g, u16* l) {
  __builtin_amdgcn_global_load_lds((__attribute__((address_space(1))) const void*)g,
                                   (__attribute__((address_space(3))) void*)l,
                                   16, 0, 0);
}

// ---------------- cast fp32 -> bf16 (x + 3 weights) + lsum zeroing ----------------
__global__ __launch_bounds__(256) void cast_all(const float* __restrict__ x,
                                                const float* __restrict__ wq,
                                                const float* __restrict__ wk,
                                                const float* __restrict__ wv,
                                                u16* __restrict__ xb,
                                                u16* __restrict__ wb,
                                                float* __restrict__ lsum) {
  int id = blockIdx.x;
  if (id < 8) {
    float4 z = {0.f, 0.f, 0.f, 0.f};
    ((float4*)lsum)[id * 256 + threadIdx.x] = z;
  }
  const float* src; u16* dst; int off;
  if (id < 2048) {                      // x: 8M elements
    src = x; dst = xb; off = id * 4096;
  } else {                              // weights: 1M each, 256 blocks per W
    int wi = id - 2048;
    int w = wi >> 8;
    src = (w == 0) ? wq : (w == 1) ? wk : wv;
    dst = wb + (size_t)w * Dd * Dd;
    off = (wi & 255) * 4096;
  }
#pragma unroll
  for (int t = 0; t < 4; t++) {
    int i = off + t * 1024 + threadIdx.x * 4;
    float4 v = *(const float4*)(src + i);
    unsigned p0 = (unsigned)f2bf(v.x) | ((unsigned)f2bf(v.y) << 16);
    unsigned p1 = (unsigned)f2bf(v.z) | ((unsigned)f2bf(v.w) << 16);
    uint2 p; p.x = p0; p.y = p1;
    *(uint2*)(dst + i) = p;
  }
}

// ---------------- shared GEMM core (C = A * B^T), bf16 in, fp32 acc ----------------
// BK=64 per barrier-pair via two BK=32 LDS buffer pairs (one vmcnt(0)+barrier
// drain per 64-K). lds: lA0|lB0|lA1|lB1, each 4096 u16 (128 rows x 32, unpadded).
// 32 KB LDS + VGPR 84 -> ~5 co-resident blocks/CU: inter-block wave overlap is
// what hides the staging/barrier serialization (r1-r5 post-mortems: every
// 1-block/CU deep-pipeline variant lost to this structure).
#define BM 128
#define BN 128

__device__ inline void gemm_tile(const u16* __restrict__ A, int lda,
                                 const u16* __restrict__ Bp, int ldb,
                                 int kBeg, int kEnd,  // multiples of 64
                                 u16* lds, f32x4 acc[4][4]) {
  u16* lA0 = lds;
  u16* lB0 = lds + 4096;
  u16* lA1 = lds + 8192;
  u16* lB1 = lds + 12288;
  const int tid  = threadIdx.x;
  const int lane = tid & 63, wave = tid >> 6;
  const int quad = lane >> 4, r16 = lane & 15;
  const int wm = (wave & 1) * 64, wn = (wave >> 1) * 64;
  const int r0 = tid >> 2, part = tid & 3;  // seg s=q*256+tid -> row=q*64+r0

  for (int k0 = kBeg; k0 < kEnd; k0 += 64) {
    __syncthreads();  // previous halves' ds_reads done before overwrite
#pragma unroll
    for (int q = 0; q < 2; q++) {
      int row = q * 64 + r0;
      int s8 = (q * 256 + tid) * 8;
      const u16* ga = A  + (size_t)row * lda + k0 + part * 8;
      const u16* gb = Bp + (size_t)row * ldb + k0 + part * 8;
      gl_lds16(ga,      lA0 + s8);
      gl_lds16(gb,      lB0 + s8);
      gl_lds16(ga + 32, lA1 + s8);
      gl_lds16(gb + 32, lB1 + s8);
    }
    __syncthreads();
#pragma unroll
    for (int h = 0; h < 2; h++) {
      const u16* la = h ? lA1 : lA0;
      const u16* lb = h ? lB1 : lB0;
      bf16x8 fa[4], fb[4];
#pragma unroll
      for (int t = 0; t < 4; t++)
        fa[t] = *(const bf16x8*)(la + (wm + t * 16 + r16) * 32 + quad * 8);
#pragma unroll
      for (int t = 0; t < 4; t++)
        fb[t] = *(const bf16x8*)(lb + (wn + t * 16 + r16) * 32 + quad * 8);
#pragma unroll
      for (int tm = 0; tm < 4; tm++)
#pragma unroll
        for (int tn = 0; tn < 4; tn++)
          acc[tm][tn] = __builtin_amdgcn_mfma_f32_16x16x32_bf16(fa[tm], fb[tn],
                                                                acc[tm][tn], 0, 0, 0);
    }
  }
}

// ---------------- QKV projection, XCD-swizzled 1-D grid (thin epilogue) ------------
// id%8 = XCD. Each XCD gets a fixed 8-row-tile stripe of A x all B tiles
// -> per-XCD L2 working set ~6 MB (FETCH 135->49 MB measured r4 of prior session).
__global__ __launch_bounds__(256) void qkv_gemm(const u16* __restrict__ xb,
                                                const u16* __restrict__ wb,
                                                u16* __restrict__ qkv) {
  __shared__ __align__(16) u16 shmem[16384];
  const int id  = blockIdx.x;          // 0..1535
  const int xcd = id & 7, j = id >> 3; // j 0..191
  const int xt  = j & 7;               // col tile (fastest within XCD)
  const int yl  = (j >> 3) & 7;
  const int zi  = j >> 6;              // 0..2
  const int y   = xcd * 8 + yl;        // row tile 0..63
  const int row0 = y * BM;             // M = B*S = 8192
  const int col0 = xt * BN;            // N = 1024
  const u16* A  = xb + (size_t)row0 * Dd;
  const u16* Bp = wb + (size_t)zi * Dd * Dd + (size_t)col0 * Dd;
  f32x4 acc[4][4];
  const f32x4 zero = {0.f, 0.f, 0.f, 0.f};
#pragma unroll
  for (int tm = 0; tm < 4; tm++)
#pragma unroll
    for (int tn = 0; tn < 4; tn++) acc[tm][tn] = zero;

  gemm_tile(A, Dd, Bp, Dd, 0, Dd, shmem, acc);

  u16* out = qkv + (size_t)zi * ((size_t)Bb * Ss * Dd);
  const int lane = threadIdx.x & 63, wave = threadIdx.x >> 6;
  const int quad = lane >> 4, r16 = lane & 15;
  const int wm = (wave & 1) * 64, wn = (wave >> 1) * 64;
#pragma unroll
  for (int tm = 0; tm < 4; tm++)
#pragma unroll
    for (int tn = 0; tn < 4; tn++) {
      int rr = row0 + wm + tm * 16 + quad * 4;
      int cc = col0 + wn + tn * 16 + r16;
#pragma unroll
      for (int r = 0; r < 4; r++)
        out[(size_t)(rr + r) * Dd + cc] = f2bf(acc[tm][tn][r]);
    }
}

// ---------------- fused scores + rowsum + V-transpose ----------------
// Blocks [0,544): lower-tri score tiles -> sc = exp(QK^T/32) (diag masked),
//   per-row partial sums atomically added into lsum (bf16-rounded p summed so
//   numerator/denominator rounding match).
// Blocks [544,1024): V transpose, grid-stride over 2048 64x64 tiles.
__global__ __launch_bounds__(256) void scores_fused(const u16* __restrict__ qb,
                                                    const u16* __restrict__ kb,
                                                    const u16* __restrict__ vb,
                                                    u16* __restrict__ sc,
                                                    u16* __restrict__ vt,
                                                    float* __restrict__ lsum) {
  __shared__ __align__(16) u16 shmem[16384];
  const int id = blockIdx.x;
  const int tid = threadIdx.x;

  if (id >= 544) {  // ---- transpose role ----
    const int bid = id - 544;            // 0..479
    u16 (*t)[72] = (u16(*)[72])shmem;    // 64x72 u16 = 9216 <= 16384
    for (int u = bid; u < 2048; u += 480) {
      const int b = u >> 9, rem = u & 511;
      const int e0 = (rem >> 5) * 64, s0 = (rem & 31) * 64;
      const u16* src = vb + (size_t)b * Ss * Dd;
      u16* dst = vt + (size_t)b * Dd * Ss;
      if (u != bid) __syncthreads();
#pragma unroll
      for (int gg = tid; gg < 512; gg += 256) {
        int row = gg >> 3, prt = gg & 7;
        uint4 v = *(const uint4*)(src + (size_t)(s0 + row) * Dd + e0 + prt * 8);
        const u16* pv = (const u16*)&v;
#pragma unroll
        for (int jj = 0; jj < 8; jj++) t[prt * 8 + jj][row] = pv[jj];
      }
      __syncthreads();
#pragma unroll
      for (int gg = tid; gg < 512; gg += 256) {
        int ee = gg >> 3, prt = gg & 7;
        uint4 v = *(const uint4*)(&t[ee][prt * 8]);
        *(uint4*)(dst + (size_t)(e0 + ee) * Ss + s0 + prt * 8) = v;
      }
    }
    return;
  }

  // ---- scores role ----
  // XCD swizzle: 17 consecutive tri-ids per XCD per batch (136 = 8*17).
  const int xcd = id & 7, j = id >> 3;   // j 0..67
  const int b = j / 17, tloc = j - b * 17;
  const int t = xcd * 17 + tloc;         // 0..135 lower-tri index
  int it = (int)((sqrtf(8.f * (float)t + 1.f) - 1.f) * 0.5f);
  while ((it + 1) * (it + 2) / 2 <= t) it++;
  while (it * (it + 1) / 2 > t) it--;
  const int jt = t - it * (it + 1) / 2;

  const u16* A  = qb + (size_t)b * Ss * Dd + (size_t)it * BM * Dd;
  const u16* Bp = kb + (size_t)b * Ss * Dd + (size_t)jt * BN * Dd;
  f32x4 acc[4][4];
  const f32x4 zero = {0.f, 0.f, 0.f, 0.f};
#pragma unroll
  for (int tm = 0; tm < 4; tm++)
#pragma unroll
    for (int tn = 0; tn < 4; tn++) acc[tm][tn] = zero;

  gemm_tile(A, Dd, Bp, Dd, 0, Dd, shmem, acc);

  // Unnormalized exp (|s/32| << 88 so fp32 exp safe without max-subtraction).
  u16* out = sc + (size_t)b * Ss * Ss;
  float* lr = lsum + (size_t)b * Ss;
  const int lane = tid & 63, wave = tid >> 6;
  const int quad = lane >> 4, r16 = lane & 15;
  const int wm = (wave & 1) * 64, wn = (wave >> 1) * 64;
#pragma unroll
  for (int tm = 0; tm < 4; tm++) {
    float psum[4] = {0.f, 0.f, 0.f, 0.f};  // per r, summed over tn
#pragma unroll
    for (int tn = 0; tn < 4; tn++) {
      int rr = it * BM + wm + tm * 16 + quad * 4;
      int cc = jt * BN + wn + tn * 16 + r16;
#pragma unroll
      for (int r = 0; r < 4; r++) {
        float p = 0.f;
        u16 h = 0;
        if (cc <= rr + r) {
          h = f2bf(__expf(acc[tm][tn][r] * 0.03125f));
          p = bf2f(h);  // sum the bf16-rounded value (matches stored numerator)
        }
        out[(size_t)(rr + r) * Ss + cc] = h;
        psum[r] += p;
      }
    }
#pragma unroll
    for (int r = 0; r < 4; r++) {
      float s = psum[r];
      s += __shfl_xor(s, 1);
      s += __shfl_xor(s, 2);
      s += __shfl_xor(s, 4);
      s += __shfl_xor(s, 8);
      if (r16 == 0) {
        int row = it * BM + wm + tm * 16 + quad * 4 + r;
        atomicAdd(&lr[row], s);
      }
    }
  }
}

// ---------------- PV: O[q,e] = (1/l[q]) * sum_k sc[q,k] Vt[e,k] ----------------
// XCD-grouped schedule: xcd=idx&7, slot=idx>>3; qp=slot>>3 (0..7), col=slot&7.
// b=qp&3, it=(qp>>2)?15-xcd:xcd. The 8 col-tiles of one (b,it) are consecutive
// slots on ONE XCD -> sc A-panel fetched ~once from HBM (not 8x) and vt[b]
// reused in that XCD's L2. Each XCD gets its {xcd, 15-xcd} -> uniform 17
// tile-K per XCD regardless of block->CU pairing granularity. 512 blocks =
// ~2 co-resident/CU (do NOT reduce to 256: 1 block/CU loses the overlap).
__global__ __launch_bounds__(256) void pv_gemm(const u16* __restrict__ sc,
                                               const u16* __restrict__ vt,
                                               const float* __restrict__ lsum,
                                               float* __restrict__ out) {
  __shared__ __align__(16) u16 shmem[16384];
  const int idx = blockIdx.x;            // 0..511
  const int xcd = idx & 7, slot = idx >> 3;
  const int qp = slot >> 3, col = slot & 7;
  const int b = qp & 3;
  const int it = (qp >> 2) ? (15 - xcd) : xcd;
  const int row0 = it * BM;
  const int col0 = col * BN;             // N = 1024
  const u16* A  = sc + (size_t)b * Ss * Ss + (size_t)row0 * Ss;
  const u16* Bp = vt + (size_t)b * Dd * Ss + (size_t)col0 * Ss;
  f32x4 acc[4][4];
  const f32x4 zero = {0.f, 0.f, 0.f, 0.f};
#pragma unroll
  for (int tm = 0; tm < 4; tm++)
#pragma unroll
    for (int tn = 0; tn < 4; tn++) acc[tm][tn] = zero;

  // causal: P[q,k]==0 for k > q (incl. zero-filled diag tile), K-loop clipped
  gemm_tile(A, Ss, Bp, Ss, 0, row0 + BM, shmem, acc);

  float* o = out + (size_t)b * Ss * Dd;
  const float* lr = lsum + (size_t)b * Ss;
  const int lane = threadIdx.x & 63, wave = threadIdx.x >> 6;
  const int quad = lane >> 4, r16 = lane & 15;
  const int wm = (wave & 1) * 64, wn = (wave >> 1) * 64;
#pragma unroll
  for (int tm = 0; tm < 4; tm++) {
    int rbase = row0 + wm + tm * 16 + quad * 4;
    float s0 = 1.f / lr[rbase], s1 = 1.f / lr[rbase + 1];
    float s2 = 1.f / lr[rbase + 2], s3 = 1.f / lr[rbase + 3];
#pragma unroll
    for (int tn = 0; tn < 4; tn++) {
      int cc = col0 + wn + tn * 16 + r16;
      o[(size_t)(rbase + 0) * Dd + cc] = acc[tm][tn][0] * s0;
      o[(size_t)(rbase + 1) * Dd + cc] = acc[tm][tn][1] * s1;
      o[(size_t)(rbase + 2) * Dd + cc] = acc[tm][tn][2] * s2;
      o[(size_t)(rbase + 3) * Dd + cc] = acc[tm][tn][3] * s3;
    }
  }
}

// ---------------- launch ----------------
// Workspace layout (bytes), total 106,987,520 (~102 MB):
//   qkv : [0, 50331648)           q,k,v bf16, each 16 MB
//   sc  : [50331648, 83886080)    exp-scores bf16, 32 MB
//   xb  : [83886080, 100663296)   x bf16 16 MB; REUSED as vt after qkv_gemm
//   wb  : [100663296, 106954752)  wq|wk|wv bf16, 6 MB
//   lsum: [106954752, 106987520)  per-row sum fp32, 32 KB (zeroed by cast_all)
extern "C" void kernel_launch(void* const* d_in, const int* in_sizes, int n_in,
                              void* d_out, int out_size, void* d_ws, size_t ws_size,
                              hipStream_t stream) {
  const float* x  = (const float*)d_in[0];
  const float* wq = (const float*)d_in[1];
  const float* wk = (const float*)d_in[2];
  const float* wv = (const float*)d_in[3];
  float* out = (float*)d_out;
  char* ws = (char*)d_ws;
  if (ws_size < 106987520u) return;  // clean fail rather than OOB corruption

  u16* qkv  = (u16*)(ws);
  u16* sc   = (u16*)(ws + 50331648u);
  u16* xb   = (u16*)(ws + 83886080u);
  u16* vt   = xb;  // alias: x dead after qkv_gemm
  u16* wb   = (u16*)(ws + 100663296u);
  float* lsum = (float*)(ws + 106954752u);

  const size_t nQ = (size_t)Bb * Ss * Dd;  // 8388608

  cast_all<<<2816, 256, 0, stream>>>(x, wq, wk, wv, xb, wb, lsum);
  qkv_gemm<<<1536, 256, 0, stream>>>(xb, wb, qkv);
  scores_fused<<<1024, 256, 0, stream>>>(qkv, qkv + nQ, qkv + 2 * nQ, sc, vt, lsum);
  pv_gemm<<<512, 256, 0, stream>>>(sc, vt, lsum, out);
}